// Round 5
// baseline (347.557 us; speedup 1.0000x reference)
//
#include <hip/hip_runtime.h>
#include <math.h>

#define N_NODES 50000
#define N_EDGES 800000
#define EP (N_EDGES + N_NODES)   // 850000 edges incl. self loops
#define NEG 0.2f
#define SCAN_BLOCKS 49           // ceil(50000/1024)

typedef __attribute__((ext_vector_type(8))) short bf16x8;
typedef __attribute__((ext_vector_type(4))) float f32x4;

// bf16 round-to-nearest-even from fp32
static __device__ __forceinline__ unsigned short bf16_rn(float f) {
    union { float f; unsigned int u; } v; v.f = f;
    unsigned int u = v.u;
    unsigned int r = (u + 0x7FFFu + ((u >> 16) & 1u)) >> 16;
    return (unsigned short)r;
}
static __device__ __forceinline__ float bf16_tof(unsigned short u) {
    union { unsigned int u; float f; } v; v.u = ((unsigned int)u) << 16;
    return v.f;
}

// ---------------- CSR build ----------------

__global__ void k_hist(const int* __restrict__ ei, int* __restrict__ counts) {
    int e = blockIdx.x * 256 + threadIdx.x;
    if (e >= EP) return;
    int d = (e < N_EDGES) ? ei[N_EDGES + e] : (e - N_EDGES);
    atomicAdd(&counts[d], 1);
}

__global__ void k_scan_block(const int* __restrict__ counts, int* __restrict__ excl,
                             int* __restrict__ bsums) {
    __shared__ int wsum[4];
    int b = blockIdx.x, t = threadIdx.x;
    int lane = t & 63, w = t >> 6;
    int i0 = b * 1024 + t * 4;
    int v0 = (i0 + 0 < N_NODES) ? counts[i0 + 0] : 0;
    int v1 = (i0 + 1 < N_NODES) ? counts[i0 + 1] : 0;
    int v2 = (i0 + 2 < N_NODES) ? counts[i0 + 2] : 0;
    int v3 = (i0 + 3 < N_NODES) ? counts[i0 + 3] : 0;
    int s = v0 + v1 + v2 + v3;
    int incl = s;
    #pragma unroll
    for (int d = 1; d < 64; d <<= 1) {
        int u = __shfl_up(incl, d);
        if (lane >= d) incl += u;
    }
    if (lane == 63) wsum[w] = incl;
    __syncthreads();
    if (t == 0) {
        int run = 0;
        #pragma unroll
        for (int i = 0; i < 4; ++i) { int x = wsum[i]; wsum[i] = run; run += x; }
        bsums[b] = run;   // block total
    }
    __syncthreads();
    int base = wsum[w] + incl - s;   // exclusive prefix of this thread's chunk
    if (i0 + 0 < N_NODES) excl[i0 + 0] = base;
    if (i0 + 1 < N_NODES) excl[i0 + 1] = base + v0;
    if (i0 + 2 < N_NODES) excl[i0 + 2] = base + v0 + v1;
    if (i0 + 3 < N_NODES) excl[i0 + 3] = base + v0 + v1 + v2;
}

__global__ void k_scan_mid(int* __restrict__ bsums) {
    int t = threadIdx.x;  // 64 threads, SCAN_BLOCKS <= 64
    int v = (t < SCAN_BLOCKS) ? bsums[t] : 0;
    int incl = v;
    #pragma unroll
    for (int d = 1; d < 64; d <<= 1) {
        int u = __shfl_up(incl, d);
        if (t >= d) incl += u;
    }
    if (t < SCAN_BLOCKS) bsums[t] = incl - v;  // exclusive
}

__global__ void k_scan_add(int* __restrict__ row_ptr, const int* __restrict__ bsums) {
    int b = blockIdx.x, t = threadIdx.x;
    int off = bsums[b];
    int i0 = b * 1024 + t * 4;
    #pragma unroll
    for (int j = 0; j < 4; ++j)
        if (i0 + j < N_NODES) row_ptr[i0 + j] += off;
    if (b == 0 && t == 0) row_ptr[N_NODES] = EP;
}

__global__ void k_scatter(const int* __restrict__ ei, const int* __restrict__ row_ptr,
                          int* __restrict__ fill, int* __restrict__ colb) {
    int e = blockIdx.x * 256 + threadIdx.x;
    if (e >= EP) return;
    int s, d;
    if (e < N_EDGES) { s = ei[e]; d = ei[N_EDGES + e]; }
    else             { s = e - N_EDGES; d = s; }
    int pos = row_ptr[d] + atomicAdd(&fill[d], 1);
    colb[pos] = s;
}

// ---------------- W1 transpose + bf16 convert: Wt[c][k] = W1[k][c] ----------------
__global__ void k_cvtW(const float* __restrict__ W1, unsigned short* __restrict__ Wt) {
    int c = blockIdx.x;   // 256
    int k = threadIdx.x;  // 256
    Wt[c * 256 + k] = bf16_rn(W1[k * 256 + c]);
}

// ---------------- Layer 1 GEMM via bf16 MFMA (LDS-free) ----------------
// xp1b[50000][256] bf16 = (x @ W1), fp32 accumulate.
// Block = 64 rows x 256 cols, 4 waves; wave w owns rows rowbase..+15, all 16
// col-tiles. K chunked by 32. No LDS: each lane loads its own A-frag from x
// (the staging lane == consuming lane, LDS round-trip was pure overhead) and
// its 16 B-frags from Wt (128 KB, L2-resident & block-invariant -> always hot).
// No barriers; compiler free to software-pipeline chunks.
//   A frag lane l: A[m=l&15][k0 + (l>>4)*8 + j]
//   B frag lane l, tile nt: Wt[nt*16+(l&15)][k0 + (l>>4)*8 + j]
//   C/D lane l, reg r: row=(l>>4)*4+r, col=l&15   (verified layouts, m89/m120)
#define GM_GRID 782   // ceil(50000/64)
__global__ __launch_bounds__(256) void
k_gemm1m(const float* __restrict__ x, const unsigned short* __restrict__ Wt,
         unsigned short* __restrict__ xp1b) {
    int t = threadIdx.x, l = t & 63, w = t >> 6;
    int rowbase = blockIdx.x * 64 + w * 16;
    int m = l & 15, kg = l >> 4;

    f32x4 acc[16];
    #pragma unroll
    for (int nt = 0; nt < 16; ++nt) acc[nt] = (f32x4){0.f, 0.f, 0.f, 0.f};

    int gra = rowbase + m;
    if (gra > N_NODES - 1) gra = N_NODES - 1;
    const float4* x4 = (const float4*)x;
    const bf16x8* WtV = (const bf16x8*)Wt;

    #pragma unroll 2
    for (int c = 0; c < 8; ++c) {
        int k0 = c * 32;
        int fi = (gra * 256 + k0 + kg * 8) >> 2;   // float4 index into x
        float4 xa = x4[fi];
        float4 xb = x4[fi + 1];
        bf16x8 aF;
        aF[0] = (short)bf16_rn(xa.x); aF[1] = (short)bf16_rn(xa.y);
        aF[2] = (short)bf16_rn(xa.z); aF[3] = (short)bf16_rn(xa.w);
        aF[4] = (short)bf16_rn(xb.x); aF[5] = (short)bf16_rn(xb.y);
        aF[6] = (short)bf16_rn(xb.z); aF[7] = (short)bf16_rn(xb.w);
        #pragma unroll
        for (int nt = 0; nt < 16; ++nt) {
            bf16x8 bF = WtV[(nt * 16 + m) * 32 + c * 4 + kg];
            acc[nt] = __builtin_amdgcn_mfma_f32_16x16x32_bf16(aF, bF, acc[nt], 0, 0, 0);
        }
    }

    // epilogue: bf16 store, C-layout row=(l>>4)*4+reg, col=nt*16+(l&15)
    int cbase = l & 15, rq = l >> 4;
    #pragma unroll
    for (int reg = 0; reg < 4; ++reg) {
        int gr = rowbase + rq * 4 + reg;
        if (gr < N_NODES) {
            #pragma unroll
            for (int nt = 0; nt < 16; ++nt)
                xp1b[gr * 256 + nt * 16 + cbase] = bf16_rn(acc[nt][reg]);
        }
    }
}

// ---------------- per-node attention logits, layer 1 (bf16 read) ----------------
__global__ void k_alphas1(const ushort4* __restrict__ xpb, const float* __restrict__ asrc,
                          const float* __restrict__ adst,
                          float* __restrict__ as1, float* __restrict__ ad1) {
    int t = threadIdx.x, l = t & 63, w = t >> 6;
    int n = blockIdx.x * 4 + w;
    ushort4 xq = xpb[n * 64 + l];
    float x0 = bf16_tof(xq.x), x1 = bf16_tof(xq.y), x2 = bf16_tof(xq.z), x3 = bf16_tof(xq.w);
    float4 a_s = ((const float4*)asrc)[l];
    float4 a_d = ((const float4*)adst)[l];
    float ds = x0 * a_s.x + x1 * a_s.y + x2 * a_s.z + x3 * a_s.w;
    float dd = x0 * a_d.x + x1 * a_d.y + x2 * a_d.z + x3 * a_d.w;
    #pragma unroll
    for (int m = 1; m < 8; m <<= 1) {
        ds += __shfl_xor(ds, m);
        dd += __shfl_xor(dd, m);
    }
    if ((l & 7) == 0) {
        int h = l >> 3;
        as1[n * 8 + h] = ds;
        ad1[n * 8 + h] = dd;
    }
}

// ---------------- fused layer-1 softmax-aggregate + ReLU + layer-2 proj/logits ----
// h-row never hits memory: after the edge loop, lane l holds h[n][4l..4l+3];
// proj2 (256->2) is two dots folded into the epilogue via 64-lane reduce.
__global__ void k_agg1(const ushort4* __restrict__ xpb, const float* __restrict__ as1,
                       const float* __restrict__ ad1, const int* __restrict__ row_ptr,
                       const int* __restrict__ colb, const float* __restrict__ b1,
                       const float* __restrict__ W2, const float* __restrict__ as2w,
                       const float* __restrict__ ad2w,
                       float* __restrict__ xp2, float* __restrict__ as2,
                       float* __restrict__ ad2) {
    int t = threadIdx.x, l = t & 63, w = t >> 6;
    int n = blockIdx.x * 4 + w;
    int hidx = l >> 3;
    float adn = ad1[n * 8 + hidx];
    int start = row_ptr[n], end = row_ptr[n + 1];
    float4 acc = {0.f, 0.f, 0.f, 0.f};
    float den = 0.f;
    int j = start;
    for (; j + 4 <= end; j += 4) {
        int s0 = colb[j], s1 = colb[j + 1], s2 = colb[j + 2], s3 = colb[j + 3];
        ushort4 x0 = xpb[s0 * 64 + l];
        ushort4 x1 = xpb[s1 * 64 + l];
        ushort4 x2 = xpb[s2 * 64 + l];
        ushort4 x3 = xpb[s3 * 64 + l];
        float e0 = as1[s0 * 8 + hidx] + adn;
        float e1 = as1[s1 * 8 + hidx] + adn;
        float e2 = as1[s2 * 8 + hidx] + adn;
        float e3 = as1[s3 * 8 + hidx] + adn;
        e0 = (e0 > 0.f) ? e0 : NEG * e0;
        e1 = (e1 > 0.f) ? e1 : NEG * e1;
        e2 = (e2 > 0.f) ? e2 : NEG * e2;
        e3 = (e3 > 0.f) ? e3 : NEG * e3;
        float p0 = __expf(e0), p1 = __expf(e1), p2 = __expf(e2), p3 = __expf(e3);
        den += (p0 + p1) + (p2 + p3);
        acc.x = fmaf(p0, bf16_tof(x0.x), acc.x);
        acc.y = fmaf(p0, bf16_tof(x0.y), acc.y);
        acc.z = fmaf(p0, bf16_tof(x0.z), acc.z);
        acc.w = fmaf(p0, bf16_tof(x0.w), acc.w);
        acc.x = fmaf(p1, bf16_tof(x1.x), acc.x);
        acc.y = fmaf(p1, bf16_tof(x1.y), acc.y);
        acc.z = fmaf(p1, bf16_tof(x1.z), acc.z);
        acc.w = fmaf(p1, bf16_tof(x1.w), acc.w);
        acc.x = fmaf(p2, bf16_tof(x2.x), acc.x);
        acc.y = fmaf(p2, bf16_tof(x2.y), acc.y);
        acc.z = fmaf(p2, bf16_tof(x2.z), acc.z);
        acc.w = fmaf(p2, bf16_tof(x2.w), acc.w);
        acc.x = fmaf(p3, bf16_tof(x3.x), acc.x);
        acc.y = fmaf(p3, bf16_tof(x3.y), acc.y);
        acc.z = fmaf(p3, bf16_tof(x3.z), acc.z);
        acc.w = fmaf(p3, bf16_tof(x3.w), acc.w);
    }
    for (; j < end; ++j) {
        int s = colb[j];
        ushort4 xv = xpb[s * 64 + l];
        float e = as1[s * 8 + hidx] + adn;
        e = (e > 0.f) ? e : NEG * e;
        float p = __expf(e);
        den += p;
        acc.x = fmaf(p, bf16_tof(xv.x), acc.x);
        acc.y = fmaf(p, bf16_tof(xv.y), acc.y);
        acc.z = fmaf(p, bf16_tof(xv.z), acc.z);
        acc.w = fmaf(p, bf16_tof(xv.w), acc.w);
    }
    float4 bv = ((const float4*)b1)[l];
    float inv = 1.f / den;
    float4 o;
    o.x = fmaxf(acc.x * inv + bv.x, 0.f);
    o.y = fmaxf(acc.y * inv + bv.y, 0.f);
    o.z = fmaxf(acc.z * inv + bv.z, 0.f);
    o.w = fmaxf(acc.w * inv + bv.w, 0.f);
    // fused proj2: W2 row-major (256,2); lane l holds channels 4l..4l+3
    float4 wa = ((const float4*)W2)[2 * l];
    float4 wb = ((const float4*)W2)[2 * l + 1];
    float d0 = o.x * wa.x + o.y * wa.z + o.z * wb.x + o.w * wb.z;
    float d1 = o.x * wa.y + o.y * wa.w + o.z * wb.y + o.w * wb.w;
    #pragma unroll
    for (int m = 1; m < 64; m <<= 1) {
        d0 += __shfl_xor(d0, m);
        d1 += __shfl_xor(d1, m);
    }
    if (l == 0) {
        xp2[2 * n] = d0;
        xp2[2 * n + 1] = d1;
        as2[n] = d0 * as2w[0] + d1 * as2w[1];
        ad2[n] = d0 * ad2w[0] + d1 * ad2w[1];
    }
}

// ---------------- fused segment-softmax + aggregate, layer 2 (2 channels) ----------------
__global__ void k_agg2(const float* __restrict__ xp2, const float* __restrict__ as2,
                       const float* __restrict__ ad2, const int* __restrict__ row_ptr,
                       const int* __restrict__ colb, const float* __restrict__ b2,
                       float* __restrict__ out) {
    int t = threadIdx.x, l = t & 63, w = t >> 6;
    int n = blockIdx.x * 4 + w;
    int start = row_ptr[n], end = row_ptr[n + 1];
    float adn = ad2[n];
    float a0 = 0.f, a1 = 0.f, den = 0.f;
    for (int j = start + l; j < end; j += 64) {
        int s = colb[j];
        float e = as2[s] + adn;
        e = (e > 0.f) ? e : NEG * e;
        float p = __expf(e);
        den += p;
        a0 = fmaf(p, xp2[2 * s], a0);
        a1 = fmaf(p, xp2[2 * s + 1], a1);
    }
    #pragma unroll
    for (int m = 1; m < 64; m <<= 1) {
        a0 += __shfl_xor(a0, m);
        a1 += __shfl_xor(a1, m);
        den += __shfl_xor(den, m);
    }
    if (l == 0) {
        out[2 * n] = a0 / den + b2[0];
        out[2 * n + 1] = a1 / den + b2[1];
    }
}

extern "C" void kernel_launch(void* const* d_in, const int* in_sizes, int n_in,
                              void* d_out, int out_size, void* d_ws, size_t ws_size,
                              hipStream_t stream) {
    const float* x     = (const float*)d_in[0];
    const int*   ei    = (const int*)d_in[1];
    const float* W1    = (const float*)d_in[2];
    const float* asrc1 = (const float*)d_in[3];
    const float* adst1 = (const float*)d_in[4];
    const float* b1    = (const float*)d_in[5];
    const float* W2    = (const float*)d_in[6];
    const float* asrc2 = (const float*)d_in[7];
    const float* adst2 = (const float*)d_in[8];
    const float* b2    = (const float*)d_in[9];
    float* out = (float*)d_out;

    char* ws = (char*)d_ws;
    unsigned short* xp1b = (unsigned short*)(ws + 0);        // 25,600,000 B (bf16)
    unsigned short* Wt   = (unsigned short*)(ws + 25600000); // 131,072 B (bf16 W1^T)
    float* as1     = (float*)(ws + 102400000);      //  1,600,000 B
    float* ad1     = (float*)(ws + 104000000);      //  1,600,000 B
    float* xp2     = (float*)(ws + 105600000);      //    400,000 B
    float* as2     = (float*)(ws + 106000000);      //    200,000 B
    float* ad2     = (float*)(ws + 106200000);      //    200,000 B
    int*   counts  = (int*)  (ws + 106400000);      //    200,000 B
    int*   fill    = (int*)  (ws + 106600000);      //    200,000 B (contig w/ counts)
    int*   row_ptr = (int*)  (ws + 106800000);      //    200,064 B
    int*   colb    = (int*)  (ws + 107000064);      //  3,400,000 B
    int*   bsums   = (int*)  (ws + 110400064);      //        256 B

    hipMemsetAsync(counts, 0, 400000, stream);      // counts + fill

    int egrid = (EP + 255) / 256;
    k_hist      <<<egrid,       256, 0, stream>>>(ei, counts);
    k_scan_block<<<SCAN_BLOCKS, 256, 0, stream>>>(counts, row_ptr, bsums);
    k_scan_mid  <<<1,            64, 0, stream>>>(bsums);
    k_scan_add  <<<SCAN_BLOCKS, 256, 0, stream>>>(row_ptr, bsums);
    k_scatter   <<<egrid,       256, 0, stream>>>(ei, row_ptr, fill, colb);

    k_cvtW      <<<256,    256, 0, stream>>>(W1, Wt);
    k_gemm1m    <<<GM_GRID, 256, 0, stream>>>(x, Wt, xp1b);
    k_alphas1   <<<12500,  256, 0, stream>>>((const ushort4*)xp1b, asrc1, adst1, as1, ad1);
    k_agg1      <<<12500,  256, 0, stream>>>((const ushort4*)xp1b, as1, ad1, row_ptr, colb,
                                             b1, W2, asrc2, adst2, xp2, as2, ad2);
    k_agg2      <<<12500,  256, 0, stream>>>(xp2, as2, ad2, row_ptr, colb, b2, out);
}

// Round 6
// 297.470 us; speedup vs baseline: 1.1684x; 1.1684x over previous
//
#include <hip/hip_runtime.h>
#include <math.h>

#define N_NODES 50000
#define N_EDGES 800000
#define EP (N_EDGES + N_NODES)   // 850000 edges incl. self loops
#define NEG 0.2f
#define SCAN_BLOCKS 49           // ceil(50000/1024)

typedef __attribute__((ext_vector_type(8))) short bf16x8;
typedef __attribute__((ext_vector_type(4))) float f32x4;

// bf16 round-to-nearest-even from fp32
static __device__ __forceinline__ unsigned short bf16_rn(float f) {
    union { float f; unsigned int u; } v; v.f = f;
    unsigned int u = v.u;
    unsigned int r = (u + 0x7FFFu + ((u >> 16) & 1u)) >> 16;
    return (unsigned short)r;
}
static __device__ __forceinline__ float bf16_tof(unsigned short u) {
    union { unsigned int u; float f; } v; v.u = ((unsigned int)u) << 16;
    return v.f;
}

// ---------------- CSR build ----------------

__global__ void k_hist(const int* __restrict__ ei, int* __restrict__ counts) {
    int e = blockIdx.x * 256 + threadIdx.x;
    if (e >= EP) return;
    int d = (e < N_EDGES) ? ei[N_EDGES + e] : (e - N_EDGES);
    atomicAdd(&counts[d], 1);
}

__global__ void k_scan_block(const int* __restrict__ counts, int* __restrict__ excl,
                             int* __restrict__ bsums) {
    __shared__ int wsum[4];
    int b = blockIdx.x, t = threadIdx.x;
    int lane = t & 63, w = t >> 6;
    int i0 = b * 1024 + t * 4;
    int v0 = (i0 + 0 < N_NODES) ? counts[i0 + 0] : 0;
    int v1 = (i0 + 1 < N_NODES) ? counts[i0 + 1] : 0;
    int v2 = (i0 + 2 < N_NODES) ? counts[i0 + 2] : 0;
    int v3 = (i0 + 3 < N_NODES) ? counts[i0 + 3] : 0;
    int s = v0 + v1 + v2 + v3;
    int incl = s;
    #pragma unroll
    for (int d = 1; d < 64; d <<= 1) {
        int u = __shfl_up(incl, d);
        if (lane >= d) incl += u;
    }
    if (lane == 63) wsum[w] = incl;
    __syncthreads();
    if (t == 0) {
        int run = 0;
        #pragma unroll
        for (int i = 0; i < 4; ++i) { int x = wsum[i]; wsum[i] = run; run += x; }
        bsums[b] = run;   // block total
    }
    __syncthreads();
    int base = wsum[w] + incl - s;   // exclusive prefix of this thread's chunk
    if (i0 + 0 < N_NODES) excl[i0 + 0] = base;
    if (i0 + 1 < N_NODES) excl[i0 + 1] = base + v0;
    if (i0 + 2 < N_NODES) excl[i0 + 2] = base + v0 + v1;
    if (i0 + 3 < N_NODES) excl[i0 + 3] = base + v0 + v1 + v2;
}

__global__ void k_scan_mid(int* __restrict__ bsums) {
    int t = threadIdx.x;  // 64 threads, SCAN_BLOCKS <= 64
    int v = (t < SCAN_BLOCKS) ? bsums[t] : 0;
    int incl = v;
    #pragma unroll
    for (int d = 1; d < 64; d <<= 1) {
        int u = __shfl_up(incl, d);
        if (t >= d) incl += u;
    }
    if (t < SCAN_BLOCKS) bsums[t] = incl - v;  // exclusive
}

__global__ void k_scan_add(int* __restrict__ row_ptr, const int* __restrict__ bsums) {
    int b = blockIdx.x, t = threadIdx.x;
    int off = bsums[b];
    int i0 = b * 1024 + t * 4;
    #pragma unroll
    for (int j = 0; j < 4; ++j)
        if (i0 + j < N_NODES) row_ptr[i0 + j] += off;
    if (b == 0 && t == 0) row_ptr[N_NODES] = EP;
}

__global__ void k_scatter(const int* __restrict__ ei, const int* __restrict__ row_ptr,
                          int* __restrict__ fill, int* __restrict__ colb) {
    int e = blockIdx.x * 256 + threadIdx.x;
    if (e >= EP) return;
    int s, d;
    if (e < N_EDGES) { s = ei[e]; d = ei[N_EDGES + e]; }
    else             { s = e - N_EDGES; d = s; }
    int pos = row_ptr[d] + atomicAdd(&fill[d], 1);
    colb[pos] = s;
}

// ---------------- W1 -> MFMA B-fragment order, bf16 ----------------
// Wfrag[c][nt][l] = 8 bf16: B[k][n] for k = c*32 + (l>>4)*8 + j, n = nt*16 + (l&15).
// Staging in the GEMM becomes a straight linear (perfectly coalesced) copy.
__global__ void k_cvtWfrag(const float* __restrict__ W1, bf16x8* __restrict__ Wfrag) {
    int ft = blockIdx.x * 256 + threadIdx.x;   // 8192 frag-lanes
    int c = ft >> 10, rem = ft & 1023;
    int nt = rem >> 6, l = rem & 63;
    int n = nt * 16 + (l & 15);
    int k0 = c * 32 + (l >> 4) * 8;
    bf16x8 f;
    #pragma unroll
    for (int j = 0; j < 8; ++j)
        f[j] = (short)bf16_rn(W1[(k0 + j) * 256 + n]);
    Wfrag[ft] = f;
}

// ---------------- Layer 1 GEMM via bf16 MFMA ----------------
// xp1b[50000][256] bf16 = (x @ W1), fp32 accumulate.
// Block = 128 threads (2 waves), 64 rows/block; wave w owns rows
// rowbase..+31 as TWO 16-row m-groups sharing each B-frag read
// (16 ds_read_b128 : 32 MFMA per chunk). B staged per K=32 chunk into LDS
// from pre-shuffled Wfrag (linear copy, coalesced); A-frags load straight
// from x to registers (no LDS round-trip; lane == consumer).
//   A frag lane l: A[m=l&15][k0+(l>>4)*8+j]
//   C/D lane l, reg r: row=(l>>4)*4+r, col=l&15   (verified layouts)
#define GM_GRID 782   // ceil(50000/64)
__global__ __launch_bounds__(128) void
k_gemm1m(const float* __restrict__ x, const bf16x8* __restrict__ Wfrag,
         unsigned short* __restrict__ xp1b) {
    __shared__ bf16x8 lds[1024];   // one chunk of B frags: 16 KB
    int t = threadIdx.x, l = t & 63, w = t >> 6;
    int rowbase = blockIdx.x * 64 + w * 32;
    int m = l & 15, kg = l >> 4;

    f32x4 acc0[16], acc1[16];
    #pragma unroll
    for (int nt = 0; nt < 16; ++nt) {
        acc0[nt] = (f32x4){0.f, 0.f, 0.f, 0.f};
        acc1[nt] = (f32x4){0.f, 0.f, 0.f, 0.f};
    }

    int r0 = rowbase + m;
    int r1 = rowbase + 16 + m;
    if (r0 > N_NODES - 1) r0 = N_NODES - 1;   // clamp (results unused)
    if (r1 > N_NODES - 1) r1 = N_NODES - 1;
    const float4* x4 = (const float4*)x;

    for (int c = 0; c < 8; ++c) {
        __syncthreads();   // previous chunk's B reads done before overwrite
        const bf16x8* src = Wfrag + c * 1024;
        #pragma unroll
        for (int q = 0; q < 8; ++q)
            lds[q * 128 + t] = src[q * 128 + t];
        __syncthreads();

        int kb = (c * 32 + kg * 8) >> 2;       // float4 col index
        float4 xa0 = x4[r0 * 64 + kb], xb0 = x4[r0 * 64 + kb + 1];
        float4 xa1 = x4[r1 * 64 + kb], xb1 = x4[r1 * 64 + kb + 1];
        bf16x8 aF0, aF1;
        aF0[0] = (short)bf16_rn(xa0.x); aF0[1] = (short)bf16_rn(xa0.y);
        aF0[2] = (short)bf16_rn(xa0.z); aF0[3] = (short)bf16_rn(xa0.w);
        aF0[4] = (short)bf16_rn(xb0.x); aF0[5] = (short)bf16_rn(xb0.y);
        aF0[6] = (short)bf16_rn(xb0.z); aF0[7] = (short)bf16_rn(xb0.w);
        aF1[0] = (short)bf16_rn(xa1.x); aF1[1] = (short)bf16_rn(xa1.y);
        aF1[2] = (short)bf16_rn(xa1.z); aF1[3] = (short)bf16_rn(xa1.w);
        aF1[4] = (short)bf16_rn(xb1.x); aF1[5] = (short)bf16_rn(xb1.y);
        aF1[6] = (short)bf16_rn(xb1.z); aF1[7] = (short)bf16_rn(xb1.w);

        #pragma unroll
        for (int nt = 0; nt < 16; ++nt) {
            bf16x8 bF = lds[nt * 64 + l];
            acc0[nt] = __builtin_amdgcn_mfma_f32_16x16x32_bf16(aF0, bF, acc0[nt], 0, 0, 0);
            acc1[nt] = __builtin_amdgcn_mfma_f32_16x16x32_bf16(aF1, bF, acc1[nt], 0, 0, 0);
        }
    }

    // epilogue: bf16 store, C-layout row=(l>>4)*4+reg, col=nt*16+(l&15)
    int cbase = l & 15, rq = l >> 4;
    #pragma unroll
    for (int reg = 0; reg < 4; ++reg) {
        int g0 = rowbase + rq * 4 + reg;
        int g1 = rowbase + 16 + rq * 4 + reg;
        if (g0 < N_NODES) {
            #pragma unroll
            for (int nt = 0; nt < 16; ++nt)
                xp1b[g0 * 256 + nt * 16 + cbase] = bf16_rn(acc0[nt][reg]);
        }
        if (g1 < N_NODES) {
            #pragma unroll
            for (int nt = 0; nt < 16; ++nt)
                xp1b[g1 * 256 + nt * 16 + cbase] = bf16_rn(acc1[nt][reg]);
        }
    }
}

// ---------------- per-node attention logits, layer 1 (bf16 read) ----------------
__global__ void k_alphas1(const ushort4* __restrict__ xpb, const float* __restrict__ asrc,
                          const float* __restrict__ adst,
                          float* __restrict__ as1, float* __restrict__ ad1) {
    int t = threadIdx.x, l = t & 63, w = t >> 6;
    int n = blockIdx.x * 4 + w;
    ushort4 xq = xpb[n * 64 + l];
    float x0 = bf16_tof(xq.x), x1 = bf16_tof(xq.y), x2 = bf16_tof(xq.z), x3 = bf16_tof(xq.w);
    float4 a_s = ((const float4*)asrc)[l];
    float4 a_d = ((const float4*)adst)[l];
    float ds = x0 * a_s.x + x1 * a_s.y + x2 * a_s.z + x3 * a_s.w;
    float dd = x0 * a_d.x + x1 * a_d.y + x2 * a_d.z + x3 * a_d.w;
    #pragma unroll
    for (int m = 1; m < 8; m <<= 1) {
        ds += __shfl_xor(ds, m);
        dd += __shfl_xor(dd, m);
    }
    if ((l & 7) == 0) {
        int h = l >> 3;
        as1[n * 8 + h] = ds;
        ad1[n * 8 + h] = dd;
    }
}

// ---------------- fused layer-1 softmax-aggregate + ReLU + layer-2 proj/logits ----
__global__ void k_agg1(const ushort4* __restrict__ xpb, const float* __restrict__ as1,
                       const float* __restrict__ ad1, const int* __restrict__ row_ptr,
                       const int* __restrict__ colb, const float* __restrict__ b1,
                       const float* __restrict__ W2, const float* __restrict__ as2w,
                       const float* __restrict__ ad2w,
                       float* __restrict__ xp2, float* __restrict__ as2,
                       float* __restrict__ ad2) {
    int t = threadIdx.x, l = t & 63, w = t >> 6;
    int n = blockIdx.x * 4 + w;
    int hidx = l >> 3;
    float adn = ad1[n * 8 + hidx];
    int start = row_ptr[n], end = row_ptr[n + 1];
    float4 acc = {0.f, 0.f, 0.f, 0.f};
    float den = 0.f;
    int j = start;
    for (; j + 4 <= end; j += 4) {
        int s0 = colb[j], s1 = colb[j + 1], s2 = colb[j + 2], s3 = colb[j + 3];
        ushort4 x0 = xpb[s0 * 64 + l];
        ushort4 x1 = xpb[s1 * 64 + l];
        ushort4 x2 = xpb[s2 * 64 + l];
        ushort4 x3 = xpb[s3 * 64 + l];
        float e0 = as1[s0 * 8 + hidx] + adn;
        float e1 = as1[s1 * 8 + hidx] + adn;
        float e2 = as1[s2 * 8 + hidx] + adn;
        float e3 = as1[s3 * 8 + hidx] + adn;
        e0 = (e0 > 0.f) ? e0 : NEG * e0;
        e1 = (e1 > 0.f) ? e1 : NEG * e1;
        e2 = (e2 > 0.f) ? e2 : NEG * e2;
        e3 = (e3 > 0.f) ? e3 : NEG * e3;
        float p0 = __expf(e0), p1 = __expf(e1), p2 = __expf(e2), p3 = __expf(e3);
        den += (p0 + p1) + (p2 + p3);
        acc.x = fmaf(p0, bf16_tof(x0.x), acc.x);
        acc.y = fmaf(p0, bf16_tof(x0.y), acc.y);
        acc.z = fmaf(p0, bf16_tof(x0.z), acc.z);
        acc.w = fmaf(p0, bf16_tof(x0.w), acc.w);
        acc.x = fmaf(p1, bf16_tof(x1.x), acc.x);
        acc.y = fmaf(p1, bf16_tof(x1.y), acc.y);
        acc.z = fmaf(p1, bf16_tof(x1.z), acc.z);
        acc.w = fmaf(p1, bf16_tof(x1.w), acc.w);
        acc.x = fmaf(p2, bf16_tof(x2.x), acc.x);
        acc.y = fmaf(p2, bf16_tof(x2.y), acc.y);
        acc.z = fmaf(p2, bf16_tof(x2.z), acc.z);
        acc.w = fmaf(p2, bf16_tof(x2.w), acc.w);
        acc.x = fmaf(p3, bf16_tof(x3.x), acc.x);
        acc.y = fmaf(p3, bf16_tof(x3.y), acc.y);
        acc.z = fmaf(p3, bf16_tof(x3.z), acc.z);
        acc.w = fmaf(p3, bf16_tof(x3.w), acc.w);
    }
    for (; j < end; ++j) {
        int s = colb[j];
        ushort4 xv = xpb[s * 64 + l];
        float e = as1[s * 8 + hidx] + adn;
        e = (e > 0.f) ? e : NEG * e;
        float p = __expf(e);
        den += p;
        acc.x = fmaf(p, bf16_tof(xv.x), acc.x);
        acc.y = fmaf(p, bf16_tof(xv.y), acc.y);
        acc.z = fmaf(p, bf16_tof(xv.z), acc.z);
        acc.w = fmaf(p, bf16_tof(xv.w), acc.w);
    }
    float4 bv = ((const float4*)b1)[l];
    float inv = 1.f / den;
    float4 o;
    o.x = fmaxf(acc.x * inv + bv.x, 0.f);
    o.y = fmaxf(acc.y * inv + bv.y, 0.f);
    o.z = fmaxf(acc.z * inv + bv.z, 0.f);
    o.w = fmaxf(acc.w * inv + bv.w, 0.f);
    // fused proj2: W2 row-major (256,2); lane l holds channels 4l..4l+3
    float4 wa = ((const float4*)W2)[2 * l];
    float4 wb = ((const float4*)W2)[2 * l + 1];
    float d0 = o.x * wa.x + o.y * wa.z + o.z * wb.x + o.w * wb.z;
    float d1 = o.x * wa.y + o.y * wa.w + o.z * wb.y + o.w * wb.w;
    #pragma unroll
    for (int m = 1; m < 64; m <<= 1) {
        d0 += __shfl_xor(d0, m);
        d1 += __shfl_xor(d1, m);
    }
    if (l == 0) {
        xp2[2 * n] = d0;
        xp2[2 * n + 1] = d1;
        as2[n] = d0 * as2w[0] + d1 * as2w[1];
        ad2[n] = d0 * ad2w[0] + d1 * ad2w[1];
    }
}

// ---------------- fused segment-softmax + aggregate, layer 2 (2 channels) ----------------
__global__ void k_agg2(const float* __restrict__ xp2, const float* __restrict__ as2,
                       const float* __restrict__ ad2, const int* __restrict__ row_ptr,
                       const int* __restrict__ colb, const float* __restrict__ b2,
                       float* __restrict__ out) {
    int t = threadIdx.x, l = t & 63, w = t >> 6;
    int n = blockIdx.x * 4 + w;
    int start = row_ptr[n], end = row_ptr[n + 1];
    float adn = ad2[n];
    float a0 = 0.f, a1 = 0.f, den = 0.f;
    for (int j = start + l; j < end; j += 64) {
        int s = colb[j];
        float e = as2[s] + adn;
        e = (e > 0.f) ? e : NEG * e;
        float p = __expf(e);
        den += p;
        a0 = fmaf(p, xp2[2 * s], a0);
        a1 = fmaf(p, xp2[2 * s + 1], a1);
    }
    #pragma unroll
    for (int m = 1; m < 64; m <<= 1) {
        a0 += __shfl_xor(a0, m);
        a1 += __shfl_xor(a1, m);
        den += __shfl_xor(den, m);
    }
    if (l == 0) {
        out[2 * n] = a0 / den + b2[0];
        out[2 * n + 1] = a1 / den + b2[1];
    }
}

extern "C" void kernel_launch(void* const* d_in, const int* in_sizes, int n_in,
                              void* d_out, int out_size, void* d_ws, size_t ws_size,
                              hipStream_t stream) {
    const float* x     = (const float*)d_in[0];
    const int*   ei    = (const int*)d_in[1];
    const float* W1    = (const float*)d_in[2];
    const float* asrc1 = (const float*)d_in[3];
    const float* adst1 = (const float*)d_in[4];
    const float* b1    = (const float*)d_in[5];
    const float* W2    = (const float*)d_in[6];
    const float* asrc2 = (const float*)d_in[7];
    const float* adst2 = (const float*)d_in[8];
    const float* b2    = (const float*)d_in[9];
    float* out = (float*)d_out;

    char* ws = (char*)d_ws;
    unsigned short* xp1b = (unsigned short*)(ws + 0);        // 25,600,000 B (bf16)
    bf16x8* Wfrag  = (bf16x8*)(ws + 25600000);      //    131,072 B (B frags)
    float* as1     = (float*)(ws + 102400000);      //  1,600,000 B
    float* ad1     = (float*)(ws + 104000000);      //  1,600,000 B
    float* xp2     = (float*)(ws + 105600000);      //    400,000 B
    float* as2     = (float*)(ws + 106000000);      //    200,000 B
    float* ad2     = (float*)(ws + 106200000);      //    200,000 B
    int*   counts  = (int*)  (ws + 106400000);      //    200,000 B
    int*   fill    = (int*)  (ws + 106600000);      //    200,000 B (contig w/ counts)
    int*   row_ptr = (int*)  (ws + 106800000);      //    200,064 B
    int*   colb    = (int*)  (ws + 107000064);      //  3,400,000 B
    int*   bsums   = (int*)  (ws + 110400064);      //        256 B

    hipMemsetAsync(counts, 0, 400000, stream);      // counts + fill

    int egrid = (EP + 255) / 256;
    k_hist      <<<egrid,       256, 0, stream>>>(ei, counts);
    k_scan_block<<<SCAN_BLOCKS, 256, 0, stream>>>(counts, row_ptr, bsums);
    k_scan_mid  <<<1,            64, 0, stream>>>(bsums);
    k_scan_add  <<<SCAN_BLOCKS, 256, 0, stream>>>(row_ptr, bsums);
    k_scatter   <<<egrid,       256, 0, stream>>>(ei, row_ptr, fill, colb);

    k_cvtWfrag  <<<32,     256, 0, stream>>>(W1, Wfrag);
    k_gemm1m    <<<GM_GRID, 128, 0, stream>>>(x, Wfrag, xp1b);
    k_alphas1   <<<12500,  256, 0, stream>>>((const ushort4*)xp1b, asrc1, adst1, as1, ad1);
    k_agg1      <<<12500,  256, 0, stream>>>((const ushort4*)xp1b, as1, ad1, row_ptr, colb,
                                             b1, W2, asrc2, adst2, xp2, as2, ad2);
    k_agg2      <<<12500,  256, 0, stream>>>(xp2, as2, ad2, row_ptr, colb, b2, out);
}

// Round 7
// 290.650 us; speedup vs baseline: 1.1958x; 1.0235x over previous
//
#include <hip/hip_runtime.h>
#include <math.h>

#define N_NODES 50000
#define N_EDGES 800000
#define EP (N_EDGES + N_NODES)   // 850000 edges incl. self loops
#define NEG 0.2f
#define SCAN_BLOCKS 49           // ceil(50000/1024)

typedef __attribute__((ext_vector_type(8))) short bf16x8;
typedef __attribute__((ext_vector_type(4))) float f32x4;
typedef __attribute__((ext_vector_type(2))) float f32x2;

// bf16 round-to-nearest-even from fp32
static __device__ __forceinline__ unsigned short bf16_rn(float f) {
    union { float f; unsigned int u; } v; v.f = f;
    unsigned int u = v.u;
    unsigned int r = (u + 0x7FFFu + ((u >> 16) & 1u)) >> 16;
    return (unsigned short)r;
}
static __device__ __forceinline__ float bf16_tof(unsigned short u) {
    union { unsigned int u; float f; } v; v.u = ((unsigned int)u) << 16;
    return v.f;
}
// unpack 2 bf16 (packed in a dword) -> f32x2 {low, high}
static __device__ __forceinline__ f32x2 bf2_unpack(unsigned int u) {
    union { unsigned int i; float f; } a, b;
    a.i = u << 16; b.i = u & 0xFFFF0000u;
    return (f32x2){a.f, b.f};
}

// ---------------- CSR build ----------------

__global__ void k_hist(const int* __restrict__ ei, int* __restrict__ counts) {
    int e = blockIdx.x * 256 + threadIdx.x;
    if (e >= EP) return;
    int d = (e < N_EDGES) ? ei[N_EDGES + e] : (e - N_EDGES);
    atomicAdd(&counts[d], 1);
}

__global__ void k_scan_block(const int* __restrict__ counts, int* __restrict__ excl,
                             int* __restrict__ bsums) {
    __shared__ int wsum[4];
    int b = blockIdx.x, t = threadIdx.x;
    int lane = t & 63, w = t >> 6;
    int i0 = b * 1024 + t * 4;
    int v0 = (i0 + 0 < N_NODES) ? counts[i0 + 0] : 0;
    int v1 = (i0 + 1 < N_NODES) ? counts[i0 + 1] : 0;
    int v2 = (i0 + 2 < N_NODES) ? counts[i0 + 2] : 0;
    int v3 = (i0 + 3 < N_NODES) ? counts[i0 + 3] : 0;
    int s = v0 + v1 + v2 + v3;
    int incl = s;
    #pragma unroll
    for (int d = 1; d < 64; d <<= 1) {
        int u = __shfl_up(incl, d);
        if (lane >= d) incl += u;
    }
    if (lane == 63) wsum[w] = incl;
    __syncthreads();
    if (t == 0) {
        int run = 0;
        #pragma unroll
        for (int i = 0; i < 4; ++i) { int x = wsum[i]; wsum[i] = run; run += x; }
        bsums[b] = run;   // block total
    }
    __syncthreads();
    int base = wsum[w] + incl - s;   // exclusive prefix of this thread's chunk
    if (i0 + 0 < N_NODES) excl[i0 + 0] = base;
    if (i0 + 1 < N_NODES) excl[i0 + 1] = base + v0;
    if (i0 + 2 < N_NODES) excl[i0 + 2] = base + v0 + v1;
    if (i0 + 3 < N_NODES) excl[i0 + 3] = base + v0 + v1 + v2;
}

// scan_mid folded in: every block wave-scans the 49 block sums itself
__global__ void k_scan_add(int* __restrict__ row_ptr, const int* __restrict__ bsums) {
    __shared__ int soff;
    int b = blockIdx.x, t = threadIdx.x;
    if (t < 64) {
        int v = (t < SCAN_BLOCKS) ? bsums[t] : 0;
        int incl = v;
        #pragma unroll
        for (int d = 1; d < 64; d <<= 1) {
            int u = __shfl_up(incl, d);
            if (t >= d) incl += u;
        }
        if (t == b) soff = incl - v;   // exclusive prefix at block b
    }
    __syncthreads();
    int off = soff;
    int i0 = b * 1024 + t * 4;
    #pragma unroll
    for (int j = 0; j < 4; ++j)
        if (i0 + j < N_NODES) row_ptr[i0 + j] += off;
    if (b == 0 && t == 0) row_ptr[N_NODES] = EP;
}

__global__ void k_scatter(const int* __restrict__ ei, const int* __restrict__ row_ptr,
                          int* __restrict__ fill, int* __restrict__ colb) {
    int e = blockIdx.x * 256 + threadIdx.x;
    if (e >= EP) return;
    int s, d;
    if (e < N_EDGES) { s = ei[e]; d = ei[N_EDGES + e]; }
    else             { s = e - N_EDGES; d = s; }
    int pos = row_ptr[d] + atomicAdd(&fill[d], 1);
    colb[pos] = s;
}

// ---------------- W1 -> MFMA B-fragment order (pi-permuted), bf16 ----------------
// Tile nt, lane l handles W column n = (l&15)*16 + nt  (pi-permutation so each
// lane's 16 accumulator tiles cover 16 CONSECUTIVE output channels -> b128
// stores + in-lane alpha dots in the GEMM epilogue).
// k = c*32 + (l>>4)*8 + j.
__global__ void k_cvtWfrag(const float* __restrict__ W1, bf16x8* __restrict__ Wfrag) {
    int ft = blockIdx.x * 256 + threadIdx.x;   // 8192 frag-lanes
    int c = ft >> 10, rem = ft & 1023;
    int nt = rem >> 6, l = rem & 63;
    int n = (l & 15) * 16 + nt;
    int k0 = c * 32 + (l >> 4) * 8;
    bf16x8 f;
    #pragma unroll
    for (int j = 0; j < 8; ++j)
        f[j] = (short)bf16_rn(W1[(k0 + j) * 256 + n]);
    Wfrag[ft] = f;
}

// ---------------- Layer 1 GEMM via bf16 MFMA + fused attention logits ----------------
// xp1b[50000][256] bf16 = (x @ W1), fp32 accumulate; as1/ad1 from fp32 accs.
// Block = 128 threads (2 waves), 64 rows/block; wave w owns 32 rows as two
// 16-row m-groups sharing each B-frag LDS read. B staged per K=32 chunk from
// pre-shuffled Wfrag (coalesced linear copy); A-frags straight to registers.
//   A frag lane l: A[m=l&15][k0+(l>>4)*8+j]
//   C/D lane l, reg r: row=(l>>4)*4+r; channels (l&15)*16 + nt  (pi-permuted)
#define GM_GRID 782   // ceil(50000/64)
__global__ __launch_bounds__(128) void
k_gemm1m(const float* __restrict__ x, const bf16x8* __restrict__ Wfrag,
         unsigned short* __restrict__ xp1b,
         const float* __restrict__ asrc, const float* __restrict__ adst,
         float* __restrict__ as1, float* __restrict__ ad1) {
    __shared__ bf16x8 lds[1024];   // one chunk of B frags: 16 KB
    int t = threadIdx.x, l = t & 63, w = t >> 6;
    int rowbase = blockIdx.x * 64 + w * 32;
    int m = l & 15, kg = l >> 4;

    f32x4 acc0[16], acc1[16];
    #pragma unroll
    for (int nt = 0; nt < 16; ++nt) {
        acc0[nt] = (f32x4){0.f, 0.f, 0.f, 0.f};
        acc1[nt] = (f32x4){0.f, 0.f, 0.f, 0.f};
    }

    int r0 = rowbase + m;
    int r1 = rowbase + 16 + m;
    if (r0 > N_NODES - 1) r0 = N_NODES - 1;   // clamp (results unused)
    if (r1 > N_NODES - 1) r1 = N_NODES - 1;
    const float4* x4 = (const float4*)x;

    for (int c = 0; c < 8; ++c) {
        __syncthreads();   // previous chunk's B reads done before overwrite
        const bf16x8* src = Wfrag + c * 1024;
        #pragma unroll
        for (int q = 0; q < 8; ++q)
            lds[q * 128 + t] = src[q * 128 + t];
        __syncthreads();

        int kb = (c * 32 + kg * 8) >> 2;       // float4 col index
        float4 xa0 = x4[r0 * 64 + kb], xb0 = x4[r0 * 64 + kb + 1];
        float4 xa1 = x4[r1 * 64 + kb], xb1 = x4[r1 * 64 + kb + 1];
        bf16x8 aF0, aF1;
        aF0[0] = (short)bf16_rn(xa0.x); aF0[1] = (short)bf16_rn(xa0.y);
        aF0[2] = (short)bf16_rn(xa0.z); aF0[3] = (short)bf16_rn(xa0.w);
        aF0[4] = (short)bf16_rn(xb0.x); aF0[5] = (short)bf16_rn(xb0.y);
        aF0[6] = (short)bf16_rn(xb0.z); aF0[7] = (short)bf16_rn(xb0.w);
        aF1[0] = (short)bf16_rn(xa1.x); aF1[1] = (short)bf16_rn(xa1.y);
        aF1[2] = (short)bf16_rn(xa1.z); aF1[3] = (short)bf16_rn(xa1.w);
        aF1[4] = (short)bf16_rn(xb1.x); aF1[5] = (short)bf16_rn(xb1.y);
        aF1[6] = (short)bf16_rn(xb1.z); aF1[7] = (short)bf16_rn(xb1.w);

        #pragma unroll
        for (int nt = 0; nt < 16; ++nt) {
            bf16x8 bF = lds[nt * 64 + l];
            acc0[nt] = __builtin_amdgcn_mfma_f32_16x16x32_bf16(aF0, bF, acc0[nt], 0, 0, 0);
            acc1[nt] = __builtin_amdgcn_mfma_f32_16x16x32_bf16(aF1, bF, acc1[nt], 0, 0, 0);
        }
    }

    // epilogue: lane holds channels cbase*16 + nt (nt=0..15) of rows rq*4+reg
    int cbase = l & 15, rq = l >> 4;
    // attention vectors for this lane's 16 channels (head = cbase>>1)
    float asV[16], adV[16];
    #pragma unroll
    for (int q = 0; q < 4; ++q) {
        float4 sa = ((const float4*)asrc)[cbase * 4 + q];
        float4 da = ((const float4*)adst)[cbase * 4 + q];
        asV[q * 4 + 0] = sa.x; asV[q * 4 + 1] = sa.y; asV[q * 4 + 2] = sa.z; asV[q * 4 + 3] = sa.w;
        adV[q * 4 + 0] = da.x; adV[q * 4 + 1] = da.y; adV[q * 4 + 2] = da.z; adV[q * 4 + 3] = da.w;
    }
    #pragma unroll
    for (int g = 0; g < 2; ++g) {
        f32x4* A = g ? acc1 : acc0;
        #pragma unroll
        for (int reg = 0; reg < 4; ++reg) {
            int gr = rowbase + g * 16 + rq * 4 + reg;
            unsigned int ob[8];
            float ps = 0.f, pd = 0.f;
            #pragma unroll
            for (int q = 0; q < 8; ++q) {
                float v0 = A[2 * q][reg], v1 = A[2 * q + 1][reg];
                ob[q] = (unsigned int)bf16_rn(v0) | ((unsigned int)bf16_rn(v1) << 16);
                ps = fmaf(v0, asV[2 * q], ps);     ps = fmaf(v1, asV[2 * q + 1], ps);
                pd = fmaf(v0, adV[2 * q], pd);     pd = fmaf(v1, adV[2 * q + 1], pd);
            }
            ps += __shfl_xor(ps, 1);
            pd += __shfl_xor(pd, 1);
            if (gr < N_NODES) {
                uint4* dst = (uint4*)(xp1b + gr * 256 + cbase * 16);
                dst[0] = make_uint4(ob[0], ob[1], ob[2], ob[3]);
                dst[1] = make_uint4(ob[4], ob[5], ob[6], ob[7]);
                if ((l & 1) == 0) {
                    as1[gr * 8 + (cbase >> 1)] = ps;
                    ad1[gr * 8 + (cbase >> 1)] = pd;
                }
            }
        }
    }
}

// ---------------- fused layer-1 softmax-aggregate + ReLU + layer-2 proj/logits ----
// f32x2 accumulate -> v_pk_fma_f32 (packed) for the message FMAs.
__global__ void k_agg1(const ushort4* __restrict__ xpb, const float* __restrict__ as1,
                       const float* __restrict__ ad1, const int* __restrict__ row_ptr,
                       const int* __restrict__ colb, const float* __restrict__ b1,
                       const float* __restrict__ W2, const float* __restrict__ as2w,
                       const float* __restrict__ ad2w,
                       float* __restrict__ xp2, float* __restrict__ as2,
                       float* __restrict__ ad2) {
    int t = threadIdx.x, l = t & 63, w = t >> 6;
    int n = blockIdx.x * 4 + w;
    int hidx = l >> 3;
    float adn = ad1[n * 8 + hidx];
    int start = row_ptr[n], end = row_ptr[n + 1];
    const uint2* xp2v = (const uint2*)xpb;
    f32x2 accA = {0.f, 0.f}, accB = {0.f, 0.f};
    float den = 0.f;
    int j = start;
    for (; j + 4 <= end; j += 4) {
        int s0 = colb[j], s1 = colb[j + 1], s2 = colb[j + 2], s3 = colb[j + 3];
        uint2 r0 = xp2v[s0 * 64 + l];
        uint2 r1 = xp2v[s1 * 64 + l];
        uint2 r2 = xp2v[s2 * 64 + l];
        uint2 r3 = xp2v[s3 * 64 + l];
        float e0 = as1[s0 * 8 + hidx] + adn;
        float e1 = as1[s1 * 8 + hidx] + adn;
        float e2 = as1[s2 * 8 + hidx] + adn;
        float e3 = as1[s3 * 8 + hidx] + adn;
        e0 = (e0 > 0.f) ? e0 : NEG * e0;
        e1 = (e1 > 0.f) ? e1 : NEG * e1;
        e2 = (e2 > 0.f) ? e2 : NEG * e2;
        e3 = (e3 > 0.f) ? e3 : NEG * e3;
        float p0 = __expf(e0), p1 = __expf(e1), p2 = __expf(e2), p3 = __expf(e3);
        den += (p0 + p1) + (p2 + p3);
        f32x2 q0 = {p0, p0}, q1 = {p1, p1}, q2 = {p2, p2}, q3 = {p3, p3};
        accA += q0 * bf2_unpack(r0.x);  accB += q0 * bf2_unpack(r0.y);
        accA += q1 * bf2_unpack(r1.x);  accB += q1 * bf2_unpack(r1.y);
        accA += q2 * bf2_unpack(r2.x);  accB += q2 * bf2_unpack(r2.y);
        accA += q3 * bf2_unpack(r3.x);  accB += q3 * bf2_unpack(r3.y);
    }
    for (; j < end; ++j) {
        int s = colb[j];
        uint2 r = xp2v[s * 64 + l];
        float e = as1[s * 8 + hidx] + adn;
        e = (e > 0.f) ? e : NEG * e;
        float p = __expf(e);
        den += p;
        f32x2 q = {p, p};
        accA += q * bf2_unpack(r.x);
        accB += q * bf2_unpack(r.y);
    }
    float4 bv = ((const float4*)b1)[l];
    float inv = 1.f / den;
    float4 o;
    o.x = fmaxf(accA[0] * inv + bv.x, 0.f);
    o.y = fmaxf(accA[1] * inv + bv.y, 0.f);
    o.z = fmaxf(accB[0] * inv + bv.z, 0.f);
    o.w = fmaxf(accB[1] * inv + bv.w, 0.f);
    // fused proj2: W2 row-major (256,2); lane l holds channels 4l..4l+3
    float4 wa = ((const float4*)W2)[2 * l];
    float4 wb = ((const float4*)W2)[2 * l + 1];
    float d0 = o.x * wa.x + o.y * wa.z + o.z * wb.x + o.w * wb.z;
    float d1 = o.x * wa.y + o.y * wa.w + o.z * wb.y + o.w * wb.w;
    #pragma unroll
    for (int m = 1; m < 64; m <<= 1) {
        d0 += __shfl_xor(d0, m);
        d1 += __shfl_xor(d1, m);
    }
    if (l == 0) {
        xp2[2 * n] = d0;
        xp2[2 * n + 1] = d1;
        as2[n] = d0 * as2w[0] + d1 * as2w[1];
        ad2[n] = d0 * ad2w[0] + d1 * ad2w[1];
    }
}

// ---------------- fused segment-softmax + aggregate, layer 2 (2 channels) ----------------
__global__ void k_agg2(const float* __restrict__ xp2, const float* __restrict__ as2,
                       const float* __restrict__ ad2, const int* __restrict__ row_ptr,
                       const int* __restrict__ colb, const float* __restrict__ b2,
                       float* __restrict__ out) {
    int t = threadIdx.x, l = t & 63, w = t >> 6;
    int n = blockIdx.x * 4 + w;
    int start = row_ptr[n], end = row_ptr[n + 1];
    float adn = ad2[n];
    float a0 = 0.f, a1 = 0.f, den = 0.f;
    for (int j = start + l; j < end; j += 64) {
        int s = colb[j];
        float e = as2[s] + adn;
        e = (e > 0.f) ? e : NEG * e;
        float p = __expf(e);
        den += p;
        a0 = fmaf(p, xp2[2 * s], a0);
        a1 = fmaf(p, xp2[2 * s + 1], a1);
    }
    #pragma unroll
    for (int m = 1; m < 64; m <<= 1) {
        a0 += __shfl_xor(a0, m);
        a1 += __shfl_xor(a1, m);
        den += __shfl_xor(den, m);
    }
    if (l == 0) {
        out[2 * n] = a0 / den + b2[0];
        out[2 * n + 1] = a1 / den + b2[1];
    }
}

extern "C" void kernel_launch(void* const* d_in, const int* in_sizes, int n_in,
                              void* d_out, int out_size, void* d_ws, size_t ws_size,
                              hipStream_t stream) {
    const float* x     = (const float*)d_in[0];
    const int*   ei    = (const int*)d_in[1];
    const float* W1    = (const float*)d_in[2];
    const float* asrc1 = (const float*)d_in[3];
    const float* adst1 = (const float*)d_in[4];
    const float* b1    = (const float*)d_in[5];
    const float* W2    = (const float*)d_in[6];
    const float* asrc2 = (const float*)d_in[7];
    const float* adst2 = (const float*)d_in[8];
    const float* b2    = (const float*)d_in[9];
    float* out = (float*)d_out;

    char* ws = (char*)d_ws;
    unsigned short* xp1b = (unsigned short*)(ws + 0);        // 25,600,000 B (bf16)
    bf16x8* Wfrag  = (bf16x8*)(ws + 25600000);      //    131,072 B (B frags)
    float* as1     = (float*)(ws + 102400000);      //  1,600,000 B
    float* ad1     = (float*)(ws + 104000000);      //  1,600,000 B
    float* xp2     = (float*)(ws + 105600000);      //    400,000 B
    float* as2     = (float*)(ws + 106000000);      //    200,000 B
    float* ad2     = (float*)(ws + 106200000);      //    200,000 B
    int*   counts  = (int*)  (ws + 106400000);      //    200,000 B
    int*   fill    = (int*)  (ws + 106600000);      //    200,000 B (contig w/ counts)
    int*   row_ptr = (int*)  (ws + 106800000);      //    200,064 B
    int*   colb    = (int*)  (ws + 107000064);      //  3,400,000 B
    int*   bsums   = (int*)  (ws + 110400064);      //        256 B

    hipMemsetAsync(counts, 0, 400000, stream);      // counts + fill

    int egrid = (EP + 255) / 256;
    k_hist      <<<egrid,       256, 0, stream>>>(ei, counts);
    k_scan_block<<<SCAN_BLOCKS, 256, 0, stream>>>(counts, row_ptr, bsums);
    k_scan_add  <<<SCAN_BLOCKS, 256, 0, stream>>>(row_ptr, bsums);
    k_scatter   <<<egrid,       256, 0, stream>>>(ei, row_ptr, fill, colb);

    k_cvtWfrag  <<<32,     256, 0, stream>>>(W1, Wfrag);
    k_gemm1m    <<<GM_GRID, 128, 0, stream>>>(x, Wfrag, xp1b, asrc1, adst1, as1, ad1);
    k_agg1      <<<12500,  256, 0, stream>>>((const ushort4*)xp1b, as1, ad1, row_ptr, colb,
                                             b1, W2, asrc2, adst2, xp2, as2, ad2);
    k_agg2      <<<12500,  256, 0, stream>>>(xp2, as2, ad2, row_ptr, colb, b2, out);
}